// Round 2
// baseline (169.902 us; speedup 1.0000x reference)
//
#include <hip/hip_runtime.h>
#include <stdint.h>

#define B  8
#define TE 2048
#define TD 256
#define H  128

// ---------- kernel 1: register-tiled GEMM (unchanged R10) ----------
// E written t-tiled: EgT[b][tb][k][tl]  (tb = t>>6, tl = t&63); F row-major [b][j][k].
#define FMA4(acc, s, wv) \
  acc.x += (s)*(wv).x; acc.y += (s)*(wv).y; acc.z += (s)*(wv).z; acc.w += (s)*(wv).w

__global__ __launch_bounds__(256) void proj_kernel(
    const float* __restrict__ enc, const float* __restrict__ dec,
    const float* __restrict__ Wa,  const float* __restrict__ Ua,
    float* __restrict__ EgT, float* __restrict__ Fg) {
  __shared__ float Ls[16 * 132];
  const float C2 = 2.8853900817779268f;  // 2*log2(e):  exp(2x) = exp2(C2*x)
  int tid = threadIdx.x;
  int bid = blockIdx.x;
  bool isE = (bid < 1024);
  int rbase = (isE ? bid : bid - 1024) * 16;
  const float* in = isE ? enc : dec;
  const float* Mg = isE ? Wa : Ua;
  int hq = tid & 31, rq = tid >> 5;
  int h0 = hq * 4, r0 = rq * 2;
  const float* rowp = in + (size_t)(rbase + r0) * H;
  const float* wp = Mg + h0;
  float4 a0{0,0,0,0}, a1{0,0,0,0};
  #pragma unroll 2
  for (int kb = 0; kb < 32; ++kb) {
    float4 rv0 = *(const float4*)(rowp + kb * 4);
    float4 rv1 = *(const float4*)(rowp + H + kb * 4);
    float4 w0 = *(const float4*)(wp + (size_t)(4 * kb + 0) * H);
    float4 w1 = *(const float4*)(wp + (size_t)(4 * kb + 1) * H);
    float4 w2 = *(const float4*)(wp + (size_t)(4 * kb + 2) * H);
    float4 w3 = *(const float4*)(wp + (size_t)(4 * kb + 3) * H);
    FMA4(a0, rv0.x, w0); FMA4(a0, rv0.y, w1); FMA4(a0, rv0.z, w2); FMA4(a0, rv0.w, w3);
    FMA4(a1, rv1.x, w0); FMA4(a1, rv1.y, w1); FMA4(a1, rv1.z, w2); FMA4(a1, rv1.w, w3);
  }
  float4 e0, e1;
  e0.x = __builtin_amdgcn_exp2f(a0.x * C2); e0.y = __builtin_amdgcn_exp2f(a0.y * C2);
  e0.z = __builtin_amdgcn_exp2f(a0.z * C2); e0.w = __builtin_amdgcn_exp2f(a0.w * C2);
  e1.x = __builtin_amdgcn_exp2f(a1.x * C2); e1.y = __builtin_amdgcn_exp2f(a1.y * C2);
  e1.z = __builtin_amdgcn_exp2f(a1.z * C2); e1.w = __builtin_amdgcn_exp2f(a1.w * C2);
  if (isE) {
    *(float4*)&Ls[(r0 + 0) * 132 + h0] = e0;
    *(float4*)&Ls[(r0 + 1) * 132 + h0] = e1;
    __syncthreads();
    int b_e = rbase >> 11, t_in = rbase & 2047;
    int tb = t_in >> 6, toff = t_in & 63;
    float* dst = EgT + ((size_t)(b_e * 32 + tb) * 128) * 64 + toff;
    #pragma unroll
    for (int jj = 0; jj < 8; ++jj) {
      int idx = jj * 256 + tid;
      int r = idx & 15, k = idx >> 4;
      dst[(size_t)k * 64 + r] = Ls[r * 132 + k];
    }
  } else {
    int b_f = rbase >> 8, j_in = rbase & 255;
    float* dst = Fg + ((size_t)(b_f * TD + j_in + r0)) * H + h0;
    *(float4*)(dst + 0 * H) = e0;
    *(float4*)(dst + 1 * H) = e1;
  }
}

// ---------- kernel 2: fused scores -> softmax -> context (R11: 8j x 1024thr) ----------
// 256 blocks (1/CU, 16 waves) x 8 j-rows: halves E/enc L2 traffic vs 4j version,
// 2x F-load amortization. e stored in place over S[j][t]; phase 3 reads e as
// broadcast b32 with imm offsets (conflict-free).
__global__ __launch_bounds__(1024, 4) void fused_kernel(
    const float* __restrict__ EgT, const float* __restrict__ Fg,
    const float* __restrict__ Va,  const float* __restrict__ enc,
    float* __restrict__ oute, float* __restrict__ outc) {
  __shared__ float S[8 * 2048];    // 64 KB: scores [j][t] -> e [j][t] -> c-partials
  __shared__ float red[32];
  int tid = threadIdx.x;
  int bid = blockIdx.x;
  int b = bid & 7, jt = bid >> 3;  // 256 blocks: consecutive ids round-robin XCDs
  int j0 = jt * 8;
  int lane = tid & 63, w = tid >> 6;   // w in 0..15
  const float4* vp = (const float4*)Va;
  float V1 = 0.f;
  #pragma unroll
  for (int q = 0; q < 32; ++q) { float4 v = vp[q]; V1 += v.x + v.y + v.z + v.w; }

  // ---- phase 1: scores[j][t] = V1 - 2*sum_k v_k/(E[t,k]*F[j,k]+1) into LDS ----
  const float4* Fp = (const float4*)(Fg + (size_t)(b * TD + j0) * H);
  const float* Ep0 = EgT + ((size_t)(b * 32 + w) * 128) * 64 + lane;        // t-tile w
  const float* Ep1 = EgT + ((size_t)(b * 32 + w + 16) * 128) * 64 + lane;   // t-tile w+16
  float s0[8], s1[8];
  #pragma unroll
  for (int j = 0; j < 8; ++j) { s0[j] = 0.f; s1[j] = 0.f; }

#define UNIT(acc, ekk, jj)                                                \
  {                                                                       \
    float d0, d1, a = 0.f;                                                \
    d0 = fmaf(ekk[0], f0[jj].x, 1.0f); d1 = fmaf(ekk[1], f0[jj].y, 1.0f); \
    a += (v0.x * d1 + v0.y * d0) * __builtin_amdgcn_rcpf(d0 * d1);        \
    d0 = fmaf(ekk[2], f0[jj].z, 1.0f); d1 = fmaf(ekk[3], f0[jj].w, 1.0f); \
    a += (v0.z * d1 + v0.w * d0) * __builtin_amdgcn_rcpf(d0 * d1);        \
    d0 = fmaf(ekk[4], f1[jj].x, 1.0f); d1 = fmaf(ekk[5], f1[jj].y, 1.0f); \
    a += (v1.x * d1 + v1.y * d0) * __builtin_amdgcn_rcpf(d0 * d1);        \
    d0 = fmaf(ekk[6], f1[jj].z, 1.0f); d1 = fmaf(ekk[7], f1[jj].w, 1.0f); \
    a += (v1.z * d1 + v1.w * d0) * __builtin_amdgcn_rcpf(d0 * d1);        \
    acc[jj] += a;                                                         \
  }

  for (int kc = 0; kc < 16; ++kc) {          // 8 k per chunk
    float4 f0[8], f1[8];
    const float4* fpc = Fp + kc * 2;
    #pragma unroll
    for (int j = 0; j < 8; ++j) {            // 16 b128 F loads, once per kc
      f0[j] = fpc[j * 32];
      f1[j] = fpc[j * 32 + 1];
    }
    float4 v0 = vp[kc * 2], v1 = vp[kc * 2 + 1];
    {
      const float* ep = Ep0 + kc * 512;
      float ek[8];
      #pragma unroll
      for (int q = 0; q < 8; ++q) ek[q] = ep[q * 64];   // 8 b32, imm offsets
      #pragma unroll
      for (int j = 0; j < 8; ++j) UNIT(s0, ek, j)
    }
    {
      const float* ep = Ep1 + kc * 512;
      float ek[8];
      #pragma unroll
      for (int q = 0; q < 8; ++q) ek[q] = ep[q * 64];
      #pragma unroll
      for (int j = 0; j < 8; ++j) UNIT(s1, ek, j)
    }
  }
  #pragma unroll
  for (int j = 0; j < 8; ++j) {
    S[j * 2048 + w * 64 + lane]        = V1 - 2.0f * s0[j];
    S[j * 2048 + (w + 16) * 64 + lane] = V1 - 2.0f * s1[j];
  }
  __syncthreads();

  // ---- phase 2: softmax per j-row (2 waves per j); e overwrites S in place ----
  int j = w >> 1, half = w & 1;
  int tb2 = half * 1024 + lane;
  float x[16];
  #pragma unroll
  for (int q = 0; q < 16; ++q) x[q] = S[j * 2048 + tb2 + q * 64];
  float m = x[0];
  #pragma unroll
  for (int q = 1; q < 16; ++q) m = fmaxf(m, x[q]);
  #pragma unroll
  for (int off = 32; off > 0; off >>= 1) m = fmaxf(m, __shfl_xor(m, off));
  if (lane == 0) red[w] = m;
  __syncthreads();
  m = fmaxf(red[j * 2], red[j * 2 + 1]);
  const float L2E = 1.4426950408889634f;
  float sum = 0.f;
  #pragma unroll
  for (int q = 0; q < 16; ++q) {
    x[q] = __builtin_amdgcn_exp2f((x[q] - m) * L2E);
    sum += x[q];
  }
  #pragma unroll
  for (int off = 32; off > 0; off >>= 1) sum += __shfl_xor(sum, off);
  if (lane == 0) red[16 + w] = sum;
  __syncthreads();
  float inv = 1.0f / (red[16 + j * 2] + red[16 + j * 2 + 1]);
  float* orow = oute + (size_t)(b * TD + j0 + j) * TE;
  #pragma unroll
  for (int q = 0; q < 16; ++q) {
    float e = x[q] * inv;
    int t = tb2 + q * 64;
    orow[t] = e;                               // coalesced 256 B/instr
    S[j * 2048 + t] = e;                       // in place: same slot it read
  }
  __syncthreads();

  // ---- phase 3: c[j][h] = sum_t e[j][t]*enc[t][h]; 32 t-slices x 64 t ----
  int hq = tid & 31, slice = tid >> 5;         // h = hq*4; t in [slice*64, slice*64+64)
  const float* encp = enc + ((size_t)b * TE + slice * 64) * H + hq * 4;
  const float* Se = S + slice * 64;            // + j*2048 + t via imm offsets
  float4 ac0{0,0,0,0}, ac1{0,0,0,0}, ac2{0,0,0,0}, ac3{0,0,0,0};
  float4 ac4{0,0,0,0}, ac5{0,0,0,0}, ac6{0,0,0,0}, ac7{0,0,0,0};
  #pragma unroll 2
  for (int t = 0; t < 64; ++t) {
    float4 ev = *(const float4*)(encp + (size_t)t * H);   // 1 KB/wave-instr
    float e0v = Se[0 * 2048 + t], e1v = Se[1 * 2048 + t]; // broadcast b32 (free)
    float e2v = Se[2 * 2048 + t], e3v = Se[3 * 2048 + t];
    float e4v = Se[4 * 2048 + t], e5v = Se[5 * 2048 + t];
    float e6v = Se[6 * 2048 + t], e7v = Se[7 * 2048 + t];
    FMA4(ac0, e0v, ev); FMA4(ac1, e1v, ev); FMA4(ac2, e2v, ev); FMA4(ac3, e3v, ev);
    FMA4(ac4, e4v, ev); FMA4(ac5, e5v, ev); FMA4(ac6, e6v, ev); FMA4(ac7, e7v, ev);
  }
  __syncthreads();                             // all e-reads done; reuse S for partials
  if (slice < 16) {                            // wave-uniform branch (waves 0-7)
    float* dst = &S[slice * 1024 + hq * 4];
    *(float4*)(dst + 0 * 128) = ac0; *(float4*)(dst + 1 * 128) = ac1;
    *(float4*)(dst + 2 * 128) = ac2; *(float4*)(dst + 3 * 128) = ac3;
    *(float4*)(dst + 4 * 128) = ac4; *(float4*)(dst + 5 * 128) = ac5;
    *(float4*)(dst + 6 * 128) = ac6; *(float4*)(dst + 7 * 128) = ac7;
  }
  __syncthreads();
  if (slice >= 16) {                           // waves 8-15: read-modify-add
    float* dst = &S[(slice - 16) * 1024 + hq * 4];
    #define RMW(J, AC) { float4 p = *(float4*)(dst + J * 128); \
      p.x += AC.x; p.y += AC.y; p.z += AC.z; p.w += AC.w; \
      *(float4*)(dst + J * 128) = p; }
    RMW(0, ac0) RMW(1, ac1) RMW(2, ac2) RMW(3, ac3)
    RMW(4, ac4) RMW(5, ac5) RMW(6, ac6) RMW(7, ac7)
    #undef RMW
  }
  __syncthreads();
  float r = 0.f;
  #pragma unroll
  for (int sl = 0; sl < 16; ++sl) r += S[sl * 1024 + tid];   // stride-1, conflict-free
  outc[(size_t)(b * TD + j0 + (tid >> 7)) * H + (tid & 127)] = r;
}

extern "C" void kernel_launch(void* const* d_in, const int* in_sizes, int n_in,
                              void* d_out, int out_size, void* d_ws, size_t ws_size,
                              hipStream_t stream) {
  (void)in_sizes; (void)n_in; (void)out_size; (void)ws_size;
  const float* enc = (const float*)d_in[0];
  const float* dec = (const float*)d_in[1];
  const float* Wa  = (const float*)d_in[2];
  const float* Ua  = (const float*)d_in[3];
  const float* Va  = (const float*)d_in[4];

  float* ws  = (float*)d_ws;
  float* EgT = ws;                                   // 8 MB  E tiled [b][tb][k][tl]
  float* Fg  = EgT + (size_t)B * TE * H;             // 1 MB  F [b][j][k]
  float* outc = (float*)d_out;                       // c [B,TD,H] fp32
  float* oute = outc + (size_t)B * TD * H;           // e [B,TD,TE] fp32

  proj_kernel<<<dim3(1152), 256, 0, stream>>>(enc, dec, Wa, Ua, EgT, Fg);
  fused_kernel<<<dim3(256), 1024, 0, stream>>>(EgT, Fg, Va, enc, oute, outc);
}

// Round 3
// 169.541 us; speedup vs baseline: 1.0021x; 1.0021x over previous
//
#include <hip/hip_runtime.h>
#include <stdint.h>

#define B  8
#define TE 2048
#define TD 256
#define H  128

// ---------- kernel 1: register-tiled GEMM (unchanged) ----------
// E written t-tiled: EgT[b][tb][k][tl]  (tb = t>>6, tl = t&63); F row-major [b][j][k].
#define FMA4(acc, s, wv) \
  acc.x += (s)*(wv).x; acc.y += (s)*(wv).y; acc.z += (s)*(wv).z; acc.w += (s)*(wv).w

__global__ __launch_bounds__(256) void proj_kernel(
    const float* __restrict__ enc, const float* __restrict__ dec,
    const float* __restrict__ Wa,  const float* __restrict__ Ua,
    float* __restrict__ EgT, float* __restrict__ Fg) {
  __shared__ float Ls[16 * 132];
  const float C2 = 2.8853900817779268f;  // 2*log2(e):  exp(2x) = exp2(C2*x)
  int tid = threadIdx.x;
  int bid = blockIdx.x;
  bool isE = (bid < 1024);
  int rbase = (isE ? bid : bid - 1024) * 16;
  const float* in = isE ? enc : dec;
  const float* Mg = isE ? Wa : Ua;
  int hq = tid & 31, rq = tid >> 5;
  int h0 = hq * 4, r0 = rq * 2;
  const float* rowp = in + (size_t)(rbase + r0) * H;
  const float* wp = Mg + h0;
  float4 a0{0,0,0,0}, a1{0,0,0,0};
  #pragma unroll 2
  for (int kb = 0; kb < 32; ++kb) {
    float4 rv0 = *(const float4*)(rowp + kb * 4);
    float4 rv1 = *(const float4*)(rowp + H + kb * 4);
    float4 w0 = *(const float4*)(wp + (size_t)(4 * kb + 0) * H);
    float4 w1 = *(const float4*)(wp + (size_t)(4 * kb + 1) * H);
    float4 w2 = *(const float4*)(wp + (size_t)(4 * kb + 2) * H);
    float4 w3 = *(const float4*)(wp + (size_t)(4 * kb + 3) * H);
    FMA4(a0, rv0.x, w0); FMA4(a0, rv0.y, w1); FMA4(a0, rv0.z, w2); FMA4(a0, rv0.w, w3);
    FMA4(a1, rv1.x, w0); FMA4(a1, rv1.y, w1); FMA4(a1, rv1.z, w2); FMA4(a1, rv1.w, w3);
  }
  float4 e0, e1;
  e0.x = __builtin_amdgcn_exp2f(a0.x * C2); e0.y = __builtin_amdgcn_exp2f(a0.y * C2);
  e0.z = __builtin_amdgcn_exp2f(a0.z * C2); e0.w = __builtin_amdgcn_exp2f(a0.w * C2);
  e1.x = __builtin_amdgcn_exp2f(a1.x * C2); e1.y = __builtin_amdgcn_exp2f(a1.y * C2);
  e1.z = __builtin_amdgcn_exp2f(a1.z * C2); e1.w = __builtin_amdgcn_exp2f(a1.w * C2);
  if (isE) {
    *(float4*)&Ls[(r0 + 0) * 132 + h0] = e0;
    *(float4*)&Ls[(r0 + 1) * 132 + h0] = e1;
    __syncthreads();
    int b_e = rbase >> 11, t_in = rbase & 2047;
    int tb = t_in >> 6, toff = t_in & 63;
    float* dst = EgT + ((size_t)(b_e * 32 + tb) * 128) * 64 + toff;
    #pragma unroll
    for (int jj = 0; jj < 8; ++jj) {
      int idx = jj * 256 + tid;
      int r = idx & 15, k = idx >> 4;
      dst[(size_t)k * 64 + r] = Ls[r * 132 + k];
    }
  } else {
    int b_f = rbase >> 8, j_in = rbase & 255;
    float* dst = Fg + ((size_t)(b_f * TD + j_in + r0)) * H + h0;
    *(float4*)(dst + 0 * H) = e0;
    *(float4*)(dst + 1 * H) = e1;
  }
}

// ---------- kernel 2: fused (R13: explicit E double-buffer + pipelined phase 3) ----------
__global__ __launch_bounds__(1024, 4) void fused_kernel(
    const float* __restrict__ EgT, const float* __restrict__ Fg,
    const float* __restrict__ Va,  const float* __restrict__ enc,
    float* __restrict__ oute, float* __restrict__ outc) {
  __shared__ float S[8 * 2048];    // 64 KB: scores [j][t] -> e [j][t] -> c-partials
  __shared__ float red[32];
  int tid = threadIdx.x;
  int bid = blockIdx.x;
  int b = bid & 7, jt = bid >> 3;  // 256 blocks: consecutive ids round-robin XCDs
  int j0 = jt * 8;
  int lane = tid & 63, w = tid >> 6;   // w in 0..15
  const float4* vp = (const float4*)Va;
  float V1 = 0.f;
  #pragma unroll
  for (int q = 0; q < 32; ++q) { float4 v = vp[q]; V1 += v.x + v.y + v.z + v.w; }

  // ---- phase 1: scores[j][t] = V1 - 2*sum_k v_k/(E[t,k]*F[j,k]+1) into LDS ----
  const float4* Fp = (const float4*)(Fg + (size_t)(b * TD + j0) * H);
  const float* Ep0 = EgT + ((size_t)(b * 32 + w) * 128) * 64 + lane;        // t-tile w
  const float* Ep1 = EgT + ((size_t)(b * 32 + w + 16) * 128) * 64 + lane;   // t-tile w+16
  float s0[8], s1[8];
  #pragma unroll
  for (int j = 0; j < 8; ++j) { s0[j] = 0.f; s1[j] = 0.f; }
  float eka[8], ekb[8];

  // 8 independent b32 loads, imm offsets 0..1792B; consumed one half-kc later
#define LOADE(dst, base, off)                                        \
  { const float* _p = (base) + (off);                                \
    dst[0] = _p[0];   dst[1] = _p[64];  dst[2] = _p[128];            \
    dst[3] = _p[192]; dst[4] = _p[256]; dst[5] = _p[320];            \
    dst[6] = _p[384]; dst[7] = _p[448]; }

#define UNIT(acc, ekk, jj)                                                \
  {                                                                       \
    float d0, d1, a = 0.f;                                                \
    d0 = fmaf(ekk[0], f0[jj].x, 1.0f); d1 = fmaf(ekk[1], f0[jj].y, 1.0f); \
    a += (v0.x * d1 + v0.y * d0) * __builtin_amdgcn_rcpf(d0 * d1);        \
    d0 = fmaf(ekk[2], f0[jj].z, 1.0f); d1 = fmaf(ekk[3], f0[jj].w, 1.0f); \
    a += (v0.z * d1 + v0.w * d0) * __builtin_amdgcn_rcpf(d0 * d1);        \
    d0 = fmaf(ekk[4], f1[jj].x, 1.0f); d1 = fmaf(ekk[5], f1[jj].y, 1.0f); \
    a += (v1.x * d1 + v1.y * d0) * __builtin_amdgcn_rcpf(d0 * d1);        \
    d0 = fmaf(ekk[6], f1[jj].z, 1.0f); d1 = fmaf(ekk[7], f1[jj].w, 1.0f); \
    a += (v1.z * d1 + v1.w * d0) * __builtin_amdgcn_rcpf(d0 * d1);        \
    acc[jj] += a;                                                         \
  }

  LOADE(eka, Ep0, 0);                        // prologue: group (kc=0, half 0)
  for (int kc = 0; kc < 16; ++kc) {
    float4 f0[8], f1[8];                     // block-uniform -> SGPR (s_load)
    const float4* fpc = Fp + kc * 2;
    #pragma unroll
    for (int j = 0; j < 8; ++j) {
      f0[j] = fpc[j * 32];
      f1[j] = fpc[j * 32 + 1];
    }
    float4 v0 = vp[kc * 2], v1 = vp[kc * 2 + 1];
    LOADE(ekb, Ep1, kc * 512);               // prefetch half 1 (cover: 224 VALU)
    #pragma unroll
    for (int j = 0; j < 8; ++j) UNIT(s0, eka, j)
    LOADE(eka, Ep0, (kc + 1) * 512);         // prefetch next kc half 0 (kc=15: benign
    #pragma unroll                           //  over-read into tile+1, never used)
    for (int j = 0; j < 8; ++j) UNIT(s1, ekb, j)
  }
  #pragma unroll
  for (int j = 0; j < 8; ++j) {
    S[j * 2048 + w * 64 + lane]        = V1 - 2.0f * s0[j];
    S[j * 2048 + (w + 16) * 64 + lane] = V1 - 2.0f * s1[j];
  }
  __syncthreads();

  // ---- phase 2: softmax per j-row (2 waves per j); e overwrites S in place ----
  int j = w >> 1, half = w & 1;
  int tb2 = half * 1024 + lane;
  float x[16];
  #pragma unroll
  for (int q = 0; q < 16; ++q) x[q] = S[j * 2048 + tb2 + q * 64];
  float m = x[0];
  #pragma unroll
  for (int q = 1; q < 16; ++q) m = fmaxf(m, x[q]);
  #pragma unroll
  for (int off = 32; off > 0; off >>= 1) m = fmaxf(m, __shfl_xor(m, off));
  if (lane == 0) red[w] = m;
  __syncthreads();
  m = fmaxf(red[j * 2], red[j * 2 + 1]);
  const float L2E = 1.4426950408889634f;
  float sum = 0.f;
  #pragma unroll
  for (int q = 0; q < 16; ++q) {
    x[q] = __builtin_amdgcn_exp2f((x[q] - m) * L2E);
    sum += x[q];
  }
  #pragma unroll
  for (int off = 32; off > 0; off >>= 1) sum += __shfl_xor(sum, off);
  if (lane == 0) red[16 + w] = sum;
  __syncthreads();
  float inv = 1.0f / (red[16 + j * 2] + red[16 + j * 2 + 1]);
  float* orow = oute + (size_t)(b * TD + j0 + j) * TE;
  #pragma unroll
  for (int q = 0; q < 16; ++q) {
    float e = x[q] * inv;
    int t = tb2 + q * 64;
    orow[t] = e;                               // coalesced 256 B/instr
    S[j * 2048 + t] = e;                       // in place: same slot it read
  }
  __syncthreads();

  // ---- phase 3: c[j][h] = sum_t e[j][t]*enc[t][h]; 32 slices x 64 t, pipelined ----
  int hq = tid & 31, slice = tid >> 5;         // h = hq*4; t in [slice*64, slice*64+64)
  const float* encp = enc + ((size_t)b * TE + slice * 64) * H + hq * 4;
  const float* Se = S + slice * 64;            // + j*2048 + t (b128 broadcast)
  float4 ac0{0,0,0,0}, ac1{0,0,0,0}, ac2{0,0,0,0}, ac3{0,0,0,0};
  float4 ac4{0,0,0,0}, ac5{0,0,0,0}, ac6{0,0,0,0}, ac7{0,0,0,0};
  float4 evA0, evA1, evA2, evA3, evB0, evB1, evB2, evB3;

#define LOADENC(d0, d1, d2, d3, t0)                         \
  d0 = *(const float4*)(encp + (size_t)(t0 + 0) * H);       \
  d1 = *(const float4*)(encp + (size_t)(t0 + 1) * H);       \
  d2 = *(const float4*)(encp + (size_t)(t0 + 2) * H);       \
  d3 = *(const float4*)(encp + (size_t)(t0 + 3) * H);

#define GROUP(t0, ex, ey, ez, ew)                                            \
  {                                                                          \
    float4 E0 = *(const float4*)&Se[0 * 2048 + (t0)];                        \
    float4 E1 = *(const float4*)&Se[1 * 2048 + (t0)];                        \
    float4 E2 = *(const float4*)&Se[2 * 2048 + (t0)];                        \
    float4 E3 = *(const float4*)&Se[3 * 2048 + (t0)];                        \
    float4 E4 = *(const float4*)&Se[4 * 2048 + (t0)];                        \
    float4 E5 = *(const float4*)&Se[5 * 2048 + (t0)];                        \
    float4 E6 = *(const float4*)&Se[6 * 2048 + (t0)];                        \
    float4 E7 = *(const float4*)&Se[7 * 2048 + (t0)];                        \
    FMA4(ac0, E0.x, ex); FMA4(ac0, E0.y, ey); FMA4(ac0, E0.z, ez); FMA4(ac0, E0.w, ew); \
    FMA4(ac1, E1.x, ex); FMA4(ac1, E1.y, ey); FMA4(ac1, E1.z, ez); FMA4(ac1, E1.w, ew); \
    FMA4(ac2, E2.x, ex); FMA4(ac2, E2.y, ey); FMA4(ac2, E2.z, ez); FMA4(ac2, E2.w, ew); \
    FMA4(ac3, E3.x, ex); FMA4(ac3, E3.y, ey); FMA4(ac3, E3.z, ez); FMA4(ac3, E3.w, ew); \
    FMA4(ac4, E4.x, ex); FMA4(ac4, E4.y, ey); FMA4(ac4, E4.z, ez); FMA4(ac4, E4.w, ew); \
    FMA4(ac5, E5.x, ex); FMA4(ac5, E5.y, ey); FMA4(ac5, E5.z, ez); FMA4(ac5, E5.w, ew); \
    FMA4(ac6, E6.x, ex); FMA4(ac6, E6.y, ey); FMA4(ac6, E6.z, ez); FMA4(ac6, E6.w, ew); \
    FMA4(ac7, E7.x, ex); FMA4(ac7, E7.y, ey); FMA4(ac7, E7.z, ez); FMA4(ac7, E7.w, ew); \
  }

  LOADENC(evA0, evA1, evA2, evA3, 0);
  #pragma unroll
  for (int tb = 0; tb < 64; tb += 8) {
    LOADENC(evB0, evB1, evB2, evB3, tb + 4);
    GROUP(tb, evA0, evA1, evA2, evA3);
    if (tb < 56) { LOADENC(evA0, evA1, evA2, evA3, tb + 8); }
    GROUP(tb + 4, evB0, evB1, evB2, evB3);
  }
  __syncthreads();                             // all e-reads done; reuse S for partials
  if (slice < 16) {                            // wave-uniform branch (waves 0-7)
    float* dst = &S[slice * 1024 + hq * 4];
    *(float4*)(dst + 0 * 128) = ac0; *(float4*)(dst + 1 * 128) = ac1;
    *(float4*)(dst + 2 * 128) = ac2; *(float4*)(dst + 3 * 128) = ac3;
    *(float4*)(dst + 4 * 128) = ac4; *(float4*)(dst + 5 * 128) = ac5;
    *(float4*)(dst + 6 * 128) = ac6; *(float4*)(dst + 7 * 128) = ac7;
  }
  __syncthreads();
  if (slice >= 16) {                           // waves 8-15: read-modify-add
    float* dst = &S[(slice - 16) * 1024 + hq * 4];
    #define RMW(J, AC) { float4 p = *(float4*)(dst + J * 128); \
      p.x += AC.x; p.y += AC.y; p.z += AC.z; p.w += AC.w; \
      *(float4*)(dst + J * 128) = p; }
    RMW(0, ac0) RMW(1, ac1) RMW(2, ac2) RMW(3, ac3)
    RMW(4, ac4) RMW(5, ac5) RMW(6, ac6) RMW(7, ac7)
    #undef RMW
  }
  __syncthreads();
  float r = 0.f;
  #pragma unroll
  for (int sl = 0; sl < 16; ++sl) r += S[sl * 1024 + tid];   // stride-1, conflict-free
  outc[(size_t)(b * TD + j0 + (tid >> 7)) * H + (tid & 127)] = r;
}

extern "C" void kernel_launch(void* const* d_in, const int* in_sizes, int n_in,
                              void* d_out, int out_size, void* d_ws, size_t ws_size,
                              hipStream_t stream) {
  (void)in_sizes; (void)n_in; (void)out_size; (void)ws_size;
  const float* enc = (const float*)d_in[0];
  const float* dec = (const float*)d_in[1];
  const float* Wa  = (const float*)d_in[2];
  const float* Ua  = (const float*)d_in[3];
  const float* Va  = (const float*)d_in[4];

  float* ws  = (float*)d_ws;
  float* EgT = ws;                                   // 8 MB  E tiled [b][tb][k][tl]
  float* Fg  = EgT + (size_t)B * TE * H;             // 1 MB  F [b][j][k]
  float* outc = (float*)d_out;                       // c [B,TD,H] fp32
  float* oute = outc + (size_t)B * TD * H;           // e [B,TD,TE] fp32

  proj_kernel<<<dim3(1152), 256, 0, stream>>>(enc, dec, Wa, Ua, EgT, Fg);
  fused_kernel<<<dim3(256), 1024, 0, stream>>>(EgT, Fg, Va, enc, oute, outc);
}